// Round 17
// baseline (2662.715 us; speedup 1.0000x reference)
//
#include <hip/hip_runtime.h>
#include <math.h>

#define NN 20000
#define EE 640000
#define NCHUNK 64
#define CLEN 10000   // EE / NCHUNK
// H=8, Ch=Kh=16, C=K=128, EC=64

typedef __attribute__((ext_vector_type(8))) short short8;
typedef __attribute__((ext_vector_type(4))) float f32x4;

// LEDGER:
//  - ws_size >= 88.2 MB (R3 passed there). R6/R15 tripwire failures were
//    S-fp32 exposing CSR atomic nondeterminism, NOT workspace overflow.
//  - Deterministic CSR (R16) = per-node edge-index order = np.add.at order.
//  - R16 absmax 0.117 included qt->bf16 (extra logit rounding). R17 reverts it.
//  - S precision irrelevant (R15). hv fp32 > hv bf16. Keep S bf16 / hv fp32.
__device__ __forceinline__ float ssp(float x) {
    float sp;
    if (x > 20.f)       sp = x;
    else if (x < -20.f) sp = __expf(x);
    else                sp = log1pf(__expf(x));
    return sp - 0.69314718055994530942f;
}

__device__ __forceinline__ float ssp_fast(float x) {
    float sp = (x > 15.f) ? x : __logf(1.f + __expf(x));
    return sp - 0.69314718055994530942f;
}

__device__ __forceinline__ unsigned short f2bf(float f) {
    unsigned u = __float_as_uint(f);
    unsigned r = (u + 0x7FFFu + ((u >> 16) & 1u)) >> 16;
    return (unsigned short)r;
}
__device__ __forceinline__ float bf2f(unsigned short h) {
    return __uint_as_float((unsigned int)h << 16);
}

__device__ __forceinline__ float4 ld4(const float* p) { return *(const float4*)p; }

__device__ __forceinline__ short8 pack8(float4 p, float4 q) {
    short8 r;
    r[0] = (short)f2bf(p.x); r[1] = (short)f2bf(p.y); r[2] = (short)f2bf(p.z); r[3] = (short)f2bf(p.w);
    r[4] = (short)f2bf(q.x); r[5] = (short)f2bf(q.y); r[6] = (short)f2bf(q.z); r[7] = (short)f2bf(q.w);
    return r;
}

// ---------------- one-time weight packing ----------------
__global__ __launch_bounds__(256) void prep_w(
    const float* __restrict__ cen_w, const float* __restrict__ out_w,
    const float* __restrict__ wk1_w, const float* __restrict__ wv1_w,
    const float* __restrict__ wk2_w, const float* __restrict__ wv2_w,
    short* __restrict__ cenw_hi, short* __restrict__ cenw_lo,
    short* __restrict__ outw_hi, short* __restrict__ outw_lo,
    short* __restrict__ w1k, short* __restrict__ w1v,
    short* __restrict__ w2k, short* __restrict__ w2v)
{
    const int b = blockIdx.x, t = threadIdx.x;
    if (b < 64) {
        int idx = b * 256 + t;
        float w = cen_w[idx];
        unsigned short hi = f2bf(w);
        cenw_hi[idx] = (short)hi;
        cenw_lo[idx] = (short)f2bf(w - bf2f(hi));
    } else if (b < 128) {
        int idx = (b - 64) * 256 + t;
        float w = out_w[idx];
        unsigned short hi = f2bf(w);
        outw_hi[idx] = (short)hi;
        outw_lo[idx] = (short)f2bf(w - bf2f(hi));
    } else {
        for (int idx = t; idx < 1024; idx += 256) {
            w1k[idx] = (short)f2bf(wk1_w[idx]);
            w1v[idx] = (short)f2bf(wv1_w[idx]);
        }
        w2k[t] = (short)f2bf(wk2_w[t]);
        w2v[t] = (short)f2bf(wv2_w[t]);
    }
}

// ---------------- per-node precompute (R7 control flow; hk bf16, hv fp32, qt fp32) ----------------
__global__ __launch_bounds__(128) void node_pre(
    const float* __restrict__ node_attr,
    const float* __restrict__ k_w, const float* __restrict__ q_w, const float* __restrict__ v_w,
    const float* __restrict__ wkl_w, const float* __restrict__ wkl_b,
    unsigned short* __restrict__ hk_g16, float* __restrict__ hv_g,
    float* __restrict__ qt_g, float* __restrict__ qb_g)
{
    const int n = blockIdx.x;
    const int t = threadIdx.x;
    __shared__ float x[128];
    __shared__ float hq[128];
    x[t] = node_attr[(size_t)n * 128 + t];
    __syncthreads();
    const int h = t >> 4, i = t & 15;
    const float* xh = &x[h * 16];
    const float* kw = &k_w[h * 256 + i * 16];
    const float* qw = &q_w[h * 256 + i * 16];
    const float* vw = &v_w[h * 256 + i * 16];
    float accK = 0.f, accQ = 0.f, accV = 0.f;
#pragma unroll
    for (int j = 0; j < 16; j++) {
        float xv = xh[j];
        accK = fmaf(xv, kw[j], accK);
        accQ = fmaf(xv, qw[j], accQ);
        accV = fmaf(xv, vw[j], accV);
    }
    hk_g16[(size_t)n * 128 + t] = f2bf(accK);
    hv_g[(size_t)n * 128 + t] = accV;
    hq[t] = accQ;
    __syncthreads();
    float qt = 0.f;
#pragma unroll
    for (int o = 0; o < 16; o++) qt = fmaf(hq[h * 16 + o], wkl_w[o * 16 + i], qt);
    qt_g[(size_t)n * 128 + t] = 0.25f * qt;
    if (i == 0) {
        float qb = 0.f;
#pragma unroll
        for (int o = 0; o < 16; o++) qb = fmaf(hq[h * 16 + o], wkl_b[o], qb);
        qb_g[(size_t)n * 8 + h] = 0.25f * qb;
    }
}

// ---------------- deterministic CSR build ----------------
__global__ void hist_kernel(const int* __restrict__ ei, int* __restrict__ hist) {
    int e = blockIdx.x * 256 + threadIdx.x;
    if (e < EE) atomicAdd(&hist[(e / CLEN) * NN + ei[e]], 1);
}

__global__ __launch_bounds__(1024) void scan_kernel(int* __restrict__ hist,
                                                    int* __restrict__ off) {
    __shared__ int arr[1024];
    const int t = threadIdx.x;
    const int STRIP = 20;
    int start = t * STRIP;
    int end = start + STRIP; if (end > NN) end = NN;
    int tot[STRIP];
    int local = 0;
    for (int n = start; n < end; n++) {
        int s = 0;
        for (int c = 0; c < NCHUNK; c++) s += hist[c * NN + n];
        tot[n - start] = s;
        local += s;
    }
    arr[t] = local;
    __syncthreads();
    for (int s = 1; s < 1024; s <<= 1) {
        int v = (t >= s) ? arr[t - s] : 0;
        __syncthreads();
        arr[t] += v;
        __syncthreads();
    }
    int running = arr[t] - local;
    for (int n = start; n < end; n++) {
        off[n] = running;
        int run = running;
        for (int c = 0; c < NCHUNK; c++) {
            int hv = hist[c * NN + n];
            hist[c * NN + n] = run;
            run += hv;
        }
        running += tot[n - start];
    }
    if (end == NN) off[NN] = running;
}

__global__ __launch_bounds__(64) void scatter_det(const int* __restrict__ ei,
                                                  int* __restrict__ base,
                                                  int* __restrict__ csr_e,
                                                  int* __restrict__ csr_col) {
    const int c = blockIdx.x;
    const int lane = threadIdx.x;
    int* bc = base + c * NN;
    const int start = c * CLEN, endc = start + CLEN;
    for (int g = start; g < endc; g += 64) {
        const int e = g + lane;
        const bool act = e < endc;
        const int row = act ? ei[e] : -1;
        int first = lane, rank = 0, total = 0;
        for (int s = 0; s < 64; s++) {
            int rs = __shfl(row, s);
            bool same = (rs == row);
            total += same ? 1 : 0;
            rank  += (same && s < lane) ? 1 : 0;
            if (same && s < first) first = s;
        }
        int old = 0;
        if (act && rank == 0) old = atomicAdd(&bc[row], total);
        old = __shfl(old, first);
        if (act) {
            int p = old + rank;
            csr_e[p] = e;
            csr_col[p] = ei[EE + e];
        }
    }
}

// ---------------- edge MLP pass (MFMA), CSR order ----------------
__global__ __launch_bounds__(256) void edge_mlp(
    const float* __restrict__ edge_attr,
    const short* __restrict__ w1k, const float* __restrict__ wk1_b,
    const short* __restrict__ w2k, const float* __restrict__ wk2_b,
    const short* __restrict__ w1v, const float* __restrict__ wv1_b,
    const short* __restrict__ w2v, const float* __restrict__ wv2_b,
    const int* __restrict__ csr_e,
    unsigned int* __restrict__ wkv_csr)
{
    __shared__ __align__(16) short lds_k[4][16][16];
    __shared__ __align__(16) short lds_v[4][16][16];

    const int t = threadIdx.x;
    const int wid = t >> 6, lane = t & 63;
    const int row = lane & 15;
    const int kg  = lane >> 4;
    const int e0  = blockIdx.x * 64 + wid * 16;

    const int src = csr_e[e0 + row];
    const float* ea = edge_attr + (size_t)src * 64 + kg * 8;
    short8 A0 = pack8(ld4(ea),      ld4(ea + 4));
    short8 A1 = pack8(ld4(ea + 32), ld4(ea + 36));

    short8 BK0 = *(const short8*)(w1k + row * 64 + kg * 8);
    short8 BK1 = *(const short8*)(w1k + row * 64 + kg * 8 + 32);
    short8 BV0 = *(const short8*)(w1v + row * 64 + kg * 8);
    short8 BV1 = *(const short8*)(w1v + row * 64 + kg * 8 + 32);

    float bk = wk1_b[row], bv = wv1_b[row];
    f32x4 ck = {bk, bk, bk, bk};
    f32x4 cv = {bv, bv, bv, bv};
    ck = __builtin_amdgcn_mfma_f32_16x16x32_bf16(A0, BK0, ck, 0, 0, 0);
    ck = __builtin_amdgcn_mfma_f32_16x16x32_bf16(A1, BK1, ck, 0, 0, 0);
    cv = __builtin_amdgcn_mfma_f32_16x16x32_bf16(A0, BV0, cv, 0, 0, 0);
    cv = __builtin_amdgcn_mfma_f32_16x16x32_bf16(A1, BV1, cv, 0, 0, 0);

#pragma unroll
    for (int r = 0; r < 4; r++) {
        lds_k[wid][kg * 4 + r][row] = (short)f2bf(ssp_fast(ck[r]));
        lds_v[wid][kg * 4 + r][row] = (short)f2bf(ssp_fast(cv[r]));
    }
    __syncthreads();

    short8 A2K = (short8)0, A2V = (short8)0, B2K = (short8)0, B2V = (short8)0;
    if (kg < 2) {
        A2K = *(const short8*)&lds_k[wid][row][kg * 8];
        A2V = *(const short8*)&lds_v[wid][row][kg * 8];
        B2K = *(const short8*)(w2k + row * 16 + kg * 8);
        B2V = *(const short8*)(w2v + row * 16 + kg * 8);
    }
    float b2k = wk2_b[row], b2v = wv2_b[row];
    f32x4 c2k = {b2k, b2k, b2k, b2k};
    f32x4 c2v = {b2v, b2v, b2v, b2v};
    c2k = __builtin_amdgcn_mfma_f32_16x16x32_bf16(A2K, B2K, c2k, 0, 0, 0);
    c2v = __builtin_amdgcn_mfma_f32_16x16x32_bf16(A2V, B2V, c2v, 0, 0, 0);

#pragma unroll
    for (int r = 0; r < 4; r++) {
        int el = kg * 4 + r;
        wkv_csr[(size_t)(e0 + el) * 16 + row] =
            (unsigned int)f2bf(c2k[r]) | ((unsigned int)f2bf(c2v[r]) << 16);
    }
}

// ---------------- attention: hk bf16, hv fp32, qt fp32, pipelined gathers ----------------
__device__ __forceinline__ void edge_step(
    uint4 hk4, float4 hv0, float4 hv1, uint4 w0, uint4 w1,
    const float* qt, float qbh, bool valid,
    float* U, float& d)
{
    unsigned int hk2[4] = {hk4.x, hk4.y, hk4.z, hk4.w};
    unsigned int ww[8] = {w0.x, w0.y, w0.z, w0.w, w1.x, w1.y, w1.z, w1.w};
    float hv[8] = {hv0.x, hv0.y, hv0.z, hv0.w, hv1.x, hv1.y, hv1.z, hv1.w};
    float term = 0.f;
    float uv[8];
#pragma unroll
    for (int i = 0; i < 8; i++) {
        unsigned hku = (i & 1) ? (hk2[i >> 1] & 0xFFFF0000u) : (hk2[i >> 1] << 16);
        float hk = __uint_as_float(hku);
        float wk = __uint_as_float(ww[i] << 16);
        float wv = __uint_as_float(ww[i] & 0xFFFF0000u);
        term = fmaf(wk * hk, qt[i], term);
        uv[i] = wv * hv[i];
    }
    term += __shfl_xor(term, 1);
    float ex = __expf(term + qbh);
    ex = valid ? ex : 0.f;
    d += ex;
#pragma unroll
    for (int i = 0; i < 8; i++) U[i] = fmaf(ex, uv[i], U[i]);
}

#define LOAD_EDGES(J0, HKA,HVA0,HVA1,WA0,WA1, HKB,HVB0,HVB1,WB0,WB1, VA,VB) do { \
    int jA_ = (J0) + eslot, jB_ = (J0) + 4 + eslot;                          \
    VA = jA_ < end; VB = jB_ < end;                                          \
    int jjA_ = VA ? jA_ : base, jjB_ = VB ? jB_ : base;                      \
    int clA_ = csr_col[jjA_], clB_ = csr_col[jjB_];                          \
    HKA = *(const uint4*)(hk_g16 + (size_t)clA_ * 128 + coff);               \
    HVA0 = *(const float4*)(hv_g + (size_t)clA_ * 128 + coff);               \
    HVA1 = *(const float4*)(hv_g + (size_t)clA_ * 128 + coff + 4);           \
    const unsigned int* wpA_ = wkv_csr + (size_t)jjA_ * 16 + half * 8;       \
    WA0 = *(const uint4*)(wpA_); WA1 = *(const uint4*)(wpA_ + 4);            \
    HKB = *(const uint4*)(hk_g16 + (size_t)clB_ * 128 + coff);               \
    HVB0 = *(const float4*)(hv_g + (size_t)clB_ * 128 + coff);               \
    HVB1 = *(const float4*)(hv_g + (size_t)clB_ * 128 + coff + 4);           \
    const unsigned int* wpB_ = wkv_csr + (size_t)jjB_ * 16 + half * 8;       \
    WB0 = *(const uint4*)(wpB_); WB1 = *(const uint4*)(wpB_ + 4);            \
} while (0)

__global__ __launch_bounds__(256) void node_attn(
    const int* __restrict__ off, const int* __restrict__ csr_col,
    const unsigned int* __restrict__ wkv_csr,
    const unsigned short* __restrict__ hk_g16, const float* __restrict__ hv_g,
    const float* __restrict__ qt_g, const float* __restrict__ qb_g,
    unsigned short* __restrict__ S_g16)
{
    const int wave = threadIdx.x >> 6;
    const int lane = threadIdx.x & 63;
    const int n = blockIdx.x * 4 + wave;
    const int half  = lane & 1;
    const int h     = (lane >> 1) & 7;
    const int eslot = lane >> 4;

    const int base = off[n], end = off[n + 1];
    const int coff = h * 16 + half * 8;

    float qt[8];
    {
        const float* q = qt_g + (size_t)n * 128 + coff;
        *(float4*)(qt + 0) = ld4(q + 0);
        *(float4*)(qt + 4) = ld4(q + 4);
    }
    const float qbh = qb_g[(size_t)n * 8 + h];

    float U[8];
#pragma unroll
    for (int i = 0; i < 8; i++) U[i] = 0.f;
    float d = 0.f;

    if (base < end) {
        uint4 hka, wa0, wa1, hkb, wb0, wb1;
        float4 hva0, hva1, hvb0, hvb1;
        bool vA, vB;
        LOAD_EDGES(base, hka, hva0, hva1, wa0, wa1, hkb, hvb0, hvb1, wb0, wb1, vA, vB);
        for (int j0 = base; j0 < end; j0 += 8) {
            uint4 nhka, nwa0, nwa1, nhkb, nwb0, nwb1;
            float4 nhva0, nhva1, nhvb0, nhvb1;
            bool nvA = false, nvB = false;
            const int nj = j0 + 8;
            if (nj < end)
                LOAD_EDGES(nj, nhka, nhva0, nhva1, nwa0, nwa1, nhkb, nhvb0, nhvb1, nwb0, nwb1, nvA, nvB);
            edge_step(hka, hva0, hva1, wa0, wa1, qt, qbh, vA, U, d);
            edge_step(hkb, hvb0, hvb1, wb0, wb1, qt, qbh, vB, U, d);
            if (nj < end) {
                hka = nhka; hva0 = nhva0; hva1 = nhva1; wa0 = nwa0; wa1 = nwa1;
                hkb = nhkb; hvb0 = nhvb0; hvb1 = nhvb1; wb0 = nwb0; wb1 = nwb1;
                vA = nvA; vB = nvB;
            }
        }
    }

#pragma unroll
    for (int s = 16; s <= 32; s <<= 1) {
        d += __shfl_xor(d, s);
#pragma unroll
        for (int i = 0; i < 8; i++) U[i] += __shfl_xor(U[i], s);
    }

    if (lane < 16) {
        const float rd = (end > base) ? (1.f / d) : 0.f;
        short8 o;
#pragma unroll
        for (int i = 0; i < 8; i++) o[i] = (short)f2bf(U[i] * rd);
        *(short8*)(S_g16 + (size_t)n * 128 + coff) = o;
    }
}

// ---------------- epilogue: wvl fold + cen GEMM + ssp + out GEMM + LN ----------------
__global__ __launch_bounds__(256) void node_out(
    const int* __restrict__ off,
    const unsigned short* __restrict__ S_g16,
    const float* __restrict__ node_attr,
    const short* __restrict__ cenw_hi, const short* __restrict__ cenw_lo, const float* __restrict__ cen_b,
    const short* __restrict__ outw_hi, const short* __restrict__ outw_lo, const float* __restrict__ out_b,
    const float* __restrict__ wvl_w, const float* __restrict__ wvl_b,
    const float* __restrict__ ln_g, const float* __restrict__ ln_b,
    float* __restrict__ out)
{
    __shared__ float S_lds[32][132];
    __shared__ float agg_lds[32][132];
    __shared__ __align__(16) short vlh_lds[32][136];
    __shared__ __align__(16) short vll_lds[32][136];
    __shared__ float wvl_lds[256];

    const int tid = threadIdx.x;
    const int w   = tid >> 6;
    const int lane = tid & 63;
    const int col = lane & 15, kg = lane >> 4;
    const int n0 = blockIdx.x * 32;
    const int mt = w & 1;
    const int ntb = (w >> 1) * 4;

    for (int idx = tid; idx < 32 * 128; idx += 256) {
        int r = idx >> 7, c = idx & 127;
        S_lds[r][c] = bf2f(S_g16[(size_t)(n0 + r) * 128 + c]);
        float v = node_attr[(size_t)(n0 + r) * 128 + c];
        unsigned short hi = f2bf(v);
        vlh_lds[r][c] = (short)hi;
        vll_lds[r][c] = (short)f2bf(v - bf2f(hi));
    }
    wvl_lds[tid] = wvl_w[tid];
    __syncthreads();

    f32x4 C1[4];
#pragma unroll
    for (int nt = 0; nt < 4; nt++) {
        float cb = cen_b[(ntb + nt) * 16 + col];
        C1[nt] = (f32x4){cb, cb, cb, cb};
    }
    {
        const int arow = mt * 16 + col;
#pragma unroll
        for (int ks = 0; ks < 4; ks++) {
            const int k0 = ks * 32 + kg * 8;
            short8 Ah = *(const short8*)&vlh_lds[arow][k0];
            short8 Al = *(const short8*)&vll_lds[arow][k0];
#pragma unroll
            for (int nt = 0; nt < 4; nt++) {
                const int brow = ((ntb + nt) * 16 + col) * 128 + k0;
                short8 Bh = *(const short8*)(cenw_hi + brow);
                short8 Bl = *(const short8*)(cenw_lo + brow);
                C1[nt] = __builtin_amdgcn_mfma_f32_16x16x32_bf16(Ah, Bh, C1[nt], 0, 0, 0);
                C1[nt] = __builtin_amdgcn_mfma_f32_16x16x32_bf16(Al, Bh, C1[nt], 0, 0, 0);
                C1[nt] = __builtin_amdgcn_mfma_f32_16x16x32_bf16(Ah, Bl, C1[nt], 0, 0, 0);
            }
        }
    }

    {
        const int r = tid >> 3;
        const int hh = tid & 7;
        const int og = hh * 16;
        float sseg[16];
#pragma unroll
        for (int q = 0; q < 4; q++) {
            float4 v = *(const float4*)&S_lds[r][og + q * 4];
            sseg[q * 4 + 0] = v.x; sseg[q * 4 + 1] = v.y;
            sseg[q * 4 + 2] = v.z; sseg[q * 4 + 3] = v.w;
        }
        const float flag = (off[n0 + r + 1] > off[n0 + r]) ? 1.f : 0.f;
#pragma unroll
        for (int oo = 0; oo < 16; oo++) {
            float acc = wvl_b[oo] * flag;
            const float* wr = &wvl_lds[oo * 16];
#pragma unroll
            for (int jj = 0; jj < 16; jj++) acc = fmaf(wr[jj], sseg[jj], acc);
            agg_lds[r][og + oo] = acc;
        }
    }
    __syncthreads();

#pragma unroll
    for (int nt = 0; nt < 4; nt++) {
        const int c = (ntb + nt) * 16 + col;
#pragma unroll
        for (int r_ = 0; r_ < 4; r_++) {
            const int rr = mt * 16 + kg * 4 + r_;
            float v = ssp(C1[nt][r_] + agg_lds[rr][c]);
            unsigned short hi = f2bf(v);
            vlh_lds[rr][c] = (short)hi;
            vll_lds[rr][c] = (short)f2bf(v - bf2f(hi));
        }
    }
    __syncthreads();

    f32x4 C2[4];
#pragma unroll
    for (int nt = 0; nt < 4; nt++) {
        float ob = out_b[(ntb + nt) * 16 + col];
        C2[nt] = (f32x4){ob, ob, ob, ob};
    }
    {
        const int arow = mt * 16 + col;
#pragma unroll
        for (int ks = 0; ks < 4; ks++) {
            const int k0 = ks * 32 + kg * 8;
            short8 Ah = *(const short8*)&vlh_lds[arow][k0];
            short8 Al = *(const short8*)&vll_lds[arow][k0];
#pragma unroll
            for (int nt = 0; nt < 4; nt++) {
                const int brow = ((ntb + nt) * 16 + col) * 128 + k0;
                short8 Bh = *(const short8*)(outw_hi + brow);
                short8 Bl = *(const short8*)(outw_lo + brow);
                C2[nt] = __builtin_amdgcn_mfma_f32_16x16x32_bf16(Ah, Bh, C2[nt], 0, 0, 0);
                C2[nt] = __builtin_amdgcn_mfma_f32_16x16x32_bf16(Al, Bh, C2[nt], 0, 0, 0);
                C2[nt] = __builtin_amdgcn_mfma_f32_16x16x32_bf16(Ah, Bl, C2[nt], 0, 0, 0);
            }
        }
    }
#pragma unroll
    for (int nt = 0; nt < 4; nt++) {
        const int c = (ntb + nt) * 16 + col;
#pragma unroll
        for (int r_ = 0; r_ < 4; r_++) {
            S_lds[mt * 16 + kg * 4 + r_][c] = C2[nt][r_];
        }
    }
    __syncthreads();

    {
        const int r = tid >> 3;
        const int g = tid & 7;
        float vals[16];
#pragma unroll
        for (int q = 0; q < 4; q++) {
            float4 v = *(const float4*)&S_lds[r][g * 16 + q * 4];
            vals[q * 4 + 0] = v.x; vals[q * 4 + 1] = v.y;
            vals[q * 4 + 2] = v.z; vals[q * 4 + 3] = v.w;
        }
        float s1 = 0.f, s2 = 0.f;
#pragma unroll
        for (int q = 0; q < 16; q++) { s1 += vals[q]; s2 = fmaf(vals[q], vals[q], s2); }
#pragma unroll
        for (int s = 1; s <= 4; s <<= 1) {
            s1 += __shfl_xor(s1, s);
            s2 += __shfl_xor(s2, s);
        }
        const float mean = s1 * (1.f / 128.f);
        const float var  = s2 * (1.f / 128.f) - mean * mean;
        const float inv  = rsqrtf(var + 1e-5f);
        float o[16];
#pragma unroll
        for (int q = 0; q < 16; q++) {
            const int c = g * 16 + q;
            o[q] = (vals[q] - mean) * inv * ln_g[c] + ln_b[c];
        }
        float* op = out + (size_t)(n0 + r) * 128 + g * 16;
#pragma unroll
        for (int q = 0; q < 4; q++) *(float4*)(op + q * 4) = *(float4*)(o + q * 4);
    }
}

extern "C" void kernel_launch(void* const* d_in, const int* in_sizes, int n_in,
                              void* d_out, int out_size, void* d_ws, size_t ws_size,
                              hipStream_t stream)
{
    (void)in_sizes; (void)n_in; (void)out_size; (void)ws_size;
    const float* node_attr = (const float*)d_in[0];
    const int*   edge_index= (const int*)d_in[1];
    const float* edge_attr = (const float*)d_in[2];
    const float* k_w  = (const float*)d_in[3];
    const float* q_w  = (const float*)d_in[4];
    const float* v_w  = (const float*)d_in[5];
    const float* wk1_w= (const float*)d_in[6];  const float* wk1_b= (const float*)d_in[7];
    const float* wk2_w= (const float*)d_in[8];  const float* wk2_b= (const float*)d_in[9];
    const float* wkl_w= (const float*)d_in[10]; const float* wkl_b= (const float*)d_in[11];
    const float* wv1_w= (const float*)d_in[12]; const float* wv1_b= (const float*)d_in[13];
    const float* wv2_w= (const float*)d_in[14]; const float* wv2_b= (const float*)d_in[15];
    const float* wvl_w= (const float*)d_in[16]; const float* wvl_b= (const float*)d_in[17];
    const float* cen_w= (const float*)d_in[18]; const float* cen_b= (const float*)d_in[19];
    const float* out_w= (const float*)d_in[20]; const float* out_b= (const float*)d_in[21];
    const float* ln_g = (const float*)d_in[22]; const float* ln_b = (const float*)d_in[23];
    float* out = (float*)d_out;

    char* ws = (char*)d_ws;
    size_t o = 0;
    auto alloc = [&](size_t bytes) -> void* {
        void* p = ws + o;
        o += (bytes + 255) & ~(size_t)255;
        return p;
    };
    unsigned short* hk_g16 = (unsigned short*)alloc((size_t)NN * 128 * 2);
    float* hv_g   = (float*)alloc((size_t)NN * 128 * 4);
    float* qt_g   = (float*)alloc((size_t)NN * 128 * 4);
    float* qb_g   = (float*)alloc((size_t)NN * 8 * 4);
    unsigned short* S_g16 = (unsigned short*)alloc((size_t)NN * 128 * 2);
    unsigned int* wkv_csr = (unsigned int*)alloc((size_t)EE * 16 * 4);
    // hist aliased into wkv_csr: dead before edge_mlp fully overwrites wkv_csr
    int* hist     = (int*)wkv_csr;   // NCHUNK*NN*4 = 5.12 MB <= 40.96 MB
    int* off      = (int*)alloc((size_t)(NN + 1) * 4);
    int* csr_e    = (int*)alloc((size_t)EE * 4);
    int* csr_col  = (int*)alloc((size_t)EE * 4);
    short* cenw_hi = (short*)alloc(16384 * 2);
    short* cenw_lo = (short*)alloc(16384 * 2);
    short* outw_hi = (short*)alloc(16384 * 2);
    short* outw_lo = (short*)alloc(16384 * 2);
    short* w1k   = (short*)alloc(1024 * 2);
    short* w1v   = (short*)alloc(1024 * 2);
    short* w2k   = (short*)alloc(256 * 2);
    short* w2v   = (short*)alloc(256 * 2);

    hipMemsetAsync(hist, 0, (size_t)NCHUNK * NN * 4, stream);

    prep_w<<<129, 256, 0, stream>>>(cen_w, out_w, wk1_w, wv1_w, wk2_w, wv2_w,
                                    cenw_hi, cenw_lo, outw_hi, outw_lo,
                                    w1k, w1v, w2k, w2v);
    node_pre<<<NN, 128, 0, stream>>>(node_attr, k_w, q_w, v_w, wkl_w, wkl_b,
                                     hk_g16, hv_g, qt_g, qb_g);
    hist_kernel<<<(EE + 255) / 256, 256, 0, stream>>>(edge_index, hist);
    scan_kernel<<<1, 1024, 0, stream>>>(hist, off);
    scatter_det<<<NCHUNK, 64, 0, stream>>>(edge_index, hist, csr_e, csr_col);
    edge_mlp<<<EE / 64, 256, 0, stream>>>(edge_attr,
                                          w1k, wk1_b, w2k, wk2_b,
                                          w1v, wv1_b, w2v, wv2_b,
                                          csr_e, wkv_csr);
    node_attn<<<NN / 4, 256, 0, stream>>>(off, csr_col, wkv_csr, hk_g16, hv_g,
                                          qt_g, qb_g, S_g16);
    node_out<<<NN / 32, 256, 0, stream>>>(off, S_g16, node_attr,
                                          cenw_hi, cenw_lo, cen_b,
                                          outw_hi, outw_lo, out_b,
                                          wvl_w, wvl_b, ln_g, ln_b, out);
}

// Round 20
// 752.867 us; speedup vs baseline: 3.5368x; 3.5368x over previous
//
#include <hip/hip_runtime.h>
#include <math.h>

#define NN 20000
#define EE 640000
#define NCHUNK 64
#define CLEN 10000   // EE / NCHUNK
// H=8, Ch=Kh=16, C=K=128, EC=64

typedef __attribute__((ext_vector_type(8))) short short8;
typedef __attribute__((ext_vector_type(4))) float f32x4;

// LEDGER:
//  - R17 (chunk-major hist, monolithic scan): GREEN, absmax exactly 0.015625.
//  - R18 {split scan + NCHUNK=256}: red. R19 {node-major hist}: red.
//  - R20 isolates the SPLIT alone: chunk-major, NCHUNK=64, all else R17-exact.
//    If red -> revert to byte-exact R17 next round (safe 2662us fallback).
__device__ __forceinline__ float ssp(float x) {
    float sp;
    if (x > 20.f)       sp = x;
    else if (x < -20.f) sp = __expf(x);
    else                sp = log1pf(__expf(x));
    return sp - 0.69314718055994530942f;
}

__device__ __forceinline__ float ssp_fast(float x) {
    float sp = (x > 15.f) ? x : __logf(1.f + __expf(x));
    return sp - 0.69314718055994530942f;
}

__device__ __forceinline__ unsigned short f2bf(float f) {
    unsigned u = __float_as_uint(f);
    unsigned r = (u + 0x7FFFu + ((u >> 16) & 1u)) >> 16;
    return (unsigned short)r;
}
__device__ __forceinline__ float bf2f(unsigned short h) {
    return __uint_as_float((unsigned int)h << 16);
}

__device__ __forceinline__ float4 ld4(const float* p) { return *(const float4*)p; }

__device__ __forceinline__ short8 pack8(float4 p, float4 q) {
    short8 r;
    r[0] = (short)f2bf(p.x); r[1] = (short)f2bf(p.y); r[2] = (short)f2bf(p.z); r[3] = (short)f2bf(p.w);
    r[4] = (short)f2bf(q.x); r[5] = (short)f2bf(q.y); r[6] = (short)f2bf(q.z); r[7] = (short)f2bf(q.w);
    return r;
}

// ---------------- one-time weight packing ----------------
__global__ __launch_bounds__(256) void prep_w(
    const float* __restrict__ cen_w, const float* __restrict__ out_w,
    const float* __restrict__ wk1_w, const float* __restrict__ wv1_w,
    const float* __restrict__ wk2_w, const float* __restrict__ wv2_w,
    short* __restrict__ cenw_hi, short* __restrict__ cenw_lo,
    short* __restrict__ outw_hi, short* __restrict__ outw_lo,
    short* __restrict__ w1k, short* __restrict__ w1v,
    short* __restrict__ w2k, short* __restrict__ w2v)
{
    const int b = blockIdx.x, t = threadIdx.x;
    if (b < 64) {
        int idx = b * 256 + t;
        float w = cen_w[idx];
        unsigned short hi = f2bf(w);
        cenw_hi[idx] = (short)hi;
        cenw_lo[idx] = (short)f2bf(w - bf2f(hi));
    } else if (b < 128) {
        int idx = (b - 64) * 256 + t;
        float w = out_w[idx];
        unsigned short hi = f2bf(w);
        outw_hi[idx] = (short)hi;
        outw_lo[idx] = (short)f2bf(w - bf2f(hi));
    } else {
        for (int idx = t; idx < 1024; idx += 256) {
            w1k[idx] = (short)f2bf(wk1_w[idx]);
            w1v[idx] = (short)f2bf(wv1_w[idx]);
        }
        w2k[t] = (short)f2bf(wk2_w[t]);
        w2v[t] = (short)f2bf(wv2_w[t]);
    }
}

// ---------------- per-node precompute (hk bf16, hv fp32, qt fp32) ----------------
__global__ __launch_bounds__(128) void node_pre(
    const float* __restrict__ node_attr,
    const float* __restrict__ k_w, const float* __restrict__ q_w, const float* __restrict__ v_w,
    const float* __restrict__ wkl_w, const float* __restrict__ wkl_b,
    unsigned short* __restrict__ hk_g16, float* __restrict__ hv_g,
    float* __restrict__ qt_g, float* __restrict__ qb_g)
{
    const int n = blockIdx.x;
    const int t = threadIdx.x;
    __shared__ float x[128];
    __shared__ float hq[128];
    x[t] = node_attr[(size_t)n * 128 + t];
    __syncthreads();
    const int h = t >> 4, i = t & 15;
    const float* xh = &x[h * 16];
    const float* kw = &k_w[h * 256 + i * 16];
    const float* qw = &q_w[h * 256 + i * 16];
    const float* vw = &v_w[h * 256 + i * 16];
    float accK = 0.f, accQ = 0.f, accV = 0.f;
#pragma unroll
    for (int j = 0; j < 16; j++) {
        float xv = xh[j];
        accK = fmaf(xv, kw[j], accK);
        accQ = fmaf(xv, qw[j], accQ);
        accV = fmaf(xv, vw[j], accV);
    }
    hk_g16[(size_t)n * 128 + t] = f2bf(accK);
    hv_g[(size_t)n * 128 + t] = accV;
    hq[t] = accQ;
    __syncthreads();
    float qt = 0.f;
#pragma unroll
    for (int o = 0; o < 16; o++) qt = fmaf(hq[h * 16 + o], wkl_w[o * 16 + i], qt);
    qt_g[(size_t)n * 128 + t] = 0.25f * qt;
    if (i == 0) {
        float qb = 0.f;
#pragma unroll
        for (int o = 0; o < 16; o++) qb = fmaf(hq[h * 16 + o], wkl_b[o], qb);
        qb_g[(size_t)n * 8 + h] = 0.25f * qb;
    }
}

// ---------------- deterministic CSR build (chunk-major hist, SPLIT scan) ----------------
__global__ void hist_kernel(const int* __restrict__ ei, int* __restrict__ hist) {
    int e = blockIdx.x * 256 + threadIdx.x;
    if (e < EE) atomicAdd(&hist[(e / CLEN) * NN + ei[e]], 1);
}

// per-node totals (parallel over nodes)
__global__ __launch_bounds__(256) void node_tot(const int* __restrict__ hist,
                                                int* __restrict__ tot) {
    int n = blockIdx.x * 256 + threadIdx.x;
    if (n < NN) {
        int s = 0;
        for (int c = 0; c < NCHUNK; c++) s += hist[c * NN + n];
        tot[n] = s;
    }
}

// exclusive scan of tot -> off (single block; cheap, R17-proven structure)
__global__ __launch_bounds__(1024) void scan_tot(const int* __restrict__ tot,
                                                 int* __restrict__ off) {
    __shared__ int arr[1024];
    const int t = threadIdx.x;
    const int STRIP = 20;
    int start = t * STRIP;
    int end = start + STRIP; if (end > NN) end = NN;
    int local = 0;
    for (int n = start; n < end; n++) local += tot[n];
    arr[t] = local;
    __syncthreads();
    for (int s = 1; s < 1024; s <<= 1) {
        int v = (t >= s) ? arr[t - s] : 0;
        __syncthreads();
        arr[t] += v;
        __syncthreads();
    }
    int running = arr[t] - local;
    for (int n = start; n < end; n++) {
        off[n] = running;
        running += tot[n];
    }
    if (end == NN) off[NN] = running;
}

// hist counts -> per-chunk bases (parallel over nodes; chunk-major walk)
__global__ __launch_bounds__(256) void chunk_base(int* __restrict__ hist,
                                                  const int* __restrict__ off) {
    int n = blockIdx.x * 256 + threadIdx.x;
    if (n < NN) {
        int run = off[n];
        for (int c = 0; c < NCHUNK; c++) {
            int hv = hist[c * NN + n];
            hist[c * NN + n] = run;
            run += hv;
        }
    }
}

// one wave per chunk; per-node slot order == edge-index order (deterministic)
__global__ __launch_bounds__(64) void scatter_det(const int* __restrict__ ei,
                                                  int* __restrict__ base,
                                                  int* __restrict__ csr_e,
                                                  int* __restrict__ csr_col) {
    const int c = blockIdx.x;
    const int lane = threadIdx.x;
    int* bc = base + c * NN;
    const int start = c * CLEN, endc = start + CLEN;
    for (int g = start; g < endc; g += 64) {
        const int e = g + lane;
        const bool act = e < endc;
        const int row = act ? ei[e] : -1;
        int first = lane, rank = 0, total = 0;
        for (int s = 0; s < 64; s++) {
            int rs = __shfl(row, s);
            bool same = (rs == row);
            total += same ? 1 : 0;
            rank  += (same && s < lane) ? 1 : 0;
            if (same && s < first) first = s;
        }
        int old = 0;
        if (act && rank == 0) old = atomicAdd(&bc[row], total);
        old = __shfl(old, first);
        if (act) {
            int p = old + rank;
            csr_e[p] = e;
            csr_col[p] = ei[EE + e];
        }
    }
}

// ---------------- edge MLP pass (MFMA), CSR order ----------------
__global__ __launch_bounds__(256) void edge_mlp(
    const float* __restrict__ edge_attr,
    const short* __restrict__ w1k, const float* __restrict__ wk1_b,
    const short* __restrict__ w2k, const float* __restrict__ wk2_b,
    const short* __restrict__ w1v, const float* __restrict__ wv1_b,
    const short* __restrict__ w2v, const float* __restrict__ wv2_b,
    const int* __restrict__ csr_e,
    unsigned int* __restrict__ wkv_csr)
{
    __shared__ __align__(16) short lds_k[4][16][16];
    __shared__ __align__(16) short lds_v[4][16][16];

    const int t = threadIdx.x;
    const int wid = t >> 6, lane = t & 63;
    const int row = lane & 15;
    const int kg  = lane >> 4;
    const int e0  = blockIdx.x * 64 + wid * 16;

    const int src = csr_e[e0 + row];
    const float* ea = edge_attr + (size_t)src * 64 + kg * 8;
    short8 A0 = pack8(ld4(ea),      ld4(ea + 4));
    short8 A1 = pack8(ld4(ea + 32), ld4(ea + 36));

    short8 BK0 = *(const short8*)(w1k + row * 64 + kg * 8);
    short8 BK1 = *(const short8*)(w1k + row * 64 + kg * 8 + 32);
    short8 BV0 = *(const short8*)(w1v + row * 64 + kg * 8);
    short8 BV1 = *(const short8*)(w1v + row * 64 + kg * 8 + 32);

    float bk = wk1_b[row], bv = wv1_b[row];
    f32x4 ck = {bk, bk, bk, bk};
    f32x4 cv = {bv, bv, bv, bv};
    ck = __builtin_amdgcn_mfma_f32_16x16x32_bf16(A0, BK0, ck, 0, 0, 0);
    ck = __builtin_amdgcn_mfma_f32_16x16x32_bf16(A1, BK1, ck, 0, 0, 0);
    cv = __builtin_amdgcn_mfma_f32_16x16x32_bf16(A0, BV0, cv, 0, 0, 0);
    cv = __builtin_amdgcn_mfma_f32_16x16x32_bf16(A1, BV1, cv, 0, 0, 0);

#pragma unroll
    for (int r = 0; r < 4; r++) {
        lds_k[wid][kg * 4 + r][row] = (short)f2bf(ssp_fast(ck[r]));
        lds_v[wid][kg * 4 + r][row] = (short)f2bf(ssp_fast(cv[r]));
    }
    __syncthreads();

    short8 A2K = (short8)0, A2V = (short8)0, B2K = (short8)0, B2V = (short8)0;
    if (kg < 2) {
        A2K = *(const short8*)&lds_k[wid][row][kg * 8];
        A2V = *(const short8*)&lds_v[wid][row][kg * 8];
        B2K = *(const short8*)(w2k + row * 16 + kg * 8);
        B2V = *(const short8*)(w2v + row * 16 + kg * 8);
    }
    float b2k = wk2_b[row], b2v = wv2_b[row];
    f32x4 c2k = {b2k, b2k, b2k, b2k};
    f32x4 c2v = {b2v, b2v, b2v, b2v};
    c2k = __builtin_amdgcn_mfma_f32_16x16x32_bf16(A2K, B2K, c2k, 0, 0, 0);
    c2v = __builtin_amdgcn_mfma_f32_16x16x32_bf16(A2V, B2V, c2v, 0, 0, 0);

#pragma unroll
    for (int r = 0; r < 4; r++) {
        int el = kg * 4 + r;
        wkv_csr[(size_t)(e0 + el) * 16 + row] =
            (unsigned int)f2bf(c2k[r]) | ((unsigned int)f2bf(c2v[r]) << 16);
    }
}

// ---------------- attention: hk bf16, hv fp32, qt fp32, pipelined gathers ----------------
__device__ __forceinline__ void edge_step(
    uint4 hk4, float4 hv0, float4 hv1, uint4 w0, uint4 w1,
    const float* qt, float qbh, bool valid,
    float* U, float& d)
{
    unsigned int hk2[4] = {hk4.x, hk4.y, hk4.z, hk4.w};
    unsigned int ww[8] = {w0.x, w0.y, w0.z, w0.w, w1.x, w1.y, w1.z, w1.w};
    float hv[8] = {hv0.x, hv0.y, hv0.z, hv0.w, hv1.x, hv1.y, hv1.z, hv1.w};
    float term = 0.f;
    float uv[8];
#pragma unroll
    for (int i = 0; i < 8; i++) {
        unsigned hku = (i & 1) ? (hk2[i >> 1] & 0xFFFF0000u) : (hk2[i >> 1] << 16);
        float hk = __uint_as_float(hku);
        float wk = __uint_as_float(ww[i] << 16);
        float wv = __uint_as_float(ww[i] & 0xFFFF0000u);
        term = fmaf(wk * hk, qt[i], term);
        uv[i] = wv * hv[i];
    }
    term += __shfl_xor(term, 1);
    float ex = __expf(term + qbh);
    ex = valid ? ex : 0.f;
    d += ex;
#pragma unroll
    for (int i = 0; i < 8; i++) U[i] = fmaf(ex, uv[i], U[i]);
}

#define LOAD_EDGES(J0, HKA,HVA0,HVA1,WA0,WA1, HKB,HVB0,HVB1,WB0,WB1, VA,VB) do { \
    int jA_ = (J0) + eslot, jB_ = (J0) + 4 + eslot;                          \
    VA = jA_ < end; VB = jB_ < end;                                          \
    int jjA_ = VA ? jA_ : base, jjB_ = VB ? jB_ : base;                      \
    int clA_ = csr_col[jjA_], clB_ = csr_col[jjB_];                          \
    HKA = *(const uint4*)(hk_g16 + (size_t)clA_ * 128 + coff);               \
    HVA0 = *(const float4*)(hv_g + (size_t)clA_ * 128 + coff);               \
    HVA1 = *(const float4*)(hv_g + (size_t)clA_ * 128 + coff + 4);           \
    const unsigned int* wpA_ = wkv_csr + (size_t)jjA_ * 16 + half * 8;       \
    WA0 = *(const uint4*)(wpA_); WA1 = *(const uint4*)(wpA_ + 4);            \
    HKB = *(const uint4*)(hk_g16 + (size_t)clB_ * 128 + coff);               \
    HVB0 = *(const float4*)(hv_g + (size_t)clB_ * 128 + coff);               \
    HVB1 = *(const float4*)(hv_g + (size_t)clB_ * 128 + coff + 4);           \
    const unsigned int* wpB_ = wkv_csr + (size_t)jjB_ * 16 + half * 8;       \
    WB0 = *(const uint4*)(wpB_); WB1 = *(const uint4*)(wpB_ + 4);            \
} while (0)

__global__ __launch_bounds__(256) void node_attn(
    const int* __restrict__ off, const int* __restrict__ csr_col,
    const unsigned int* __restrict__ wkv_csr,
    const unsigned short* __restrict__ hk_g16, const float* __restrict__ hv_g,
    const float* __restrict__ qt_g, const float* __restrict__ qb_g,
    unsigned short* __restrict__ S_g16)
{
    const int wave = threadIdx.x >> 6;
    const int lane = threadIdx.x & 63;
    const int n = blockIdx.x * 4 + wave;
    const int half  = lane & 1;
    const int h     = (lane >> 1) & 7;
    const int eslot = lane >> 4;

    const int base = off[n], end = off[n + 1];
    const int coff = h * 16 + half * 8;

    float qt[8];
    {
        const float* q = qt_g + (size_t)n * 128 + coff;
        *(float4*)(qt + 0) = ld4(q + 0);
        *(float4*)(qt + 4) = ld4(q + 4);
    }
    const float qbh = qb_g[(size_t)n * 8 + h];

    float U[8];
#pragma unroll
    for (int i = 0; i < 8; i++) U[i] = 0.f;
    float d = 0.f;

    if (base < end) {
        uint4 hka, wa0, wa1, hkb, wb0, wb1;
        float4 hva0, hva1, hvb0, hvb1;
        bool vA, vB;
        LOAD_EDGES(base, hka, hva0, hva1, wa0, wa1, hkb, hvb0, hvb1, wb0, wb1, vA, vB);
        for (int j0 = base; j0 < end; j0 += 8) {
            uint4 nhka, nwa0, nwa1, nhkb, nwb0, nwb1;
            float4 nhva0, nhva1, nhvb0, nhvb1;
            bool nvA = false, nvB = false;
            const int nj = j0 + 8;
            if (nj < end)
                LOAD_EDGES(nj, nhka, nhva0, nhva1, nwa0, nwa1, nhkb, nhvb0, nhvb1, nwb0, nwb1, nvA, nvB);
            edge_step(hka, hva0, hva1, wa0, wa1, qt, qbh, vA, U, d);
            edge_step(hkb, hvb0, hvb1, wb0, wb1, qt, qbh, vB, U, d);
            if (nj < end) {
                hka = nhka; hva0 = nhva0; hva1 = nhva1; wa0 = nwa0; wa1 = nwa1;
                hkb = nhkb; hvb0 = nhvb0; hvb1 = nhvb1; wb0 = nwb0; wb1 = nwb1;
                vA = nvA; vB = nvB;
            }
        }
    }

#pragma unroll
    for (int s = 16; s <= 32; s <<= 1) {
        d += __shfl_xor(d, s);
#pragma unroll
        for (int i = 0; i < 8; i++) U[i] += __shfl_xor(U[i], s);
    }

    if (lane < 16) {
        const float rd = (end > base) ? (1.f / d) : 0.f;
        short8 o;
#pragma unroll
        for (int i = 0; i < 8; i++) o[i] = (short)f2bf(U[i] * rd);
        *(short8*)(S_g16 + (size_t)n * 128 + coff) = o;
    }
}

// ---------------- epilogue: wvl fold + cen GEMM + ssp + out GEMM + LN ----------------
__global__ __launch_bounds__(256) void node_out(
    const int* __restrict__ off,
    const unsigned short* __restrict__ S_g16,
    const float* __restrict__ node_attr,
    const short* __restrict__ cenw_hi, const short* __restrict__ cenw_lo, const float* __restrict__ cen_b,
    const short* __restrict__ outw_hi, const short* __restrict__ outw_lo, const float* __restrict__ out_b,
    const float* __restrict__ wvl_w, const float* __restrict__ wvl_b,
    const float* __restrict__ ln_g, const float* __restrict__ ln_b,
    float* __restrict__ out)
{
    __shared__ float S_lds[32][132];
    __shared__ float agg_lds[32][132];
    __shared__ __align__(16) short vlh_lds[32][136];
    __shared__ __align__(16) short vll_lds[32][136];
    __shared__ float wvl_lds[256];

    const int tid = threadIdx.x;
    const int w   = tid >> 6;
    const int lane = tid & 63;
    const int col = lane & 15, kg = lane >> 4;
    const int n0 = blockIdx.x * 32;
    const int mt = w & 1;
    const int ntb = (w >> 1) * 4;

    for (int idx = tid; idx < 32 * 128; idx += 256) {
        int r = idx >> 7, c = idx & 127;
        S_lds[r][c] = bf2f(S_g16[(size_t)(n0 + r) * 128 + c]);
        float v = node_attr[(size_t)(n0 + r) * 128 + c];
        unsigned short hi = f2bf(v);
        vlh_lds[r][c] = (short)hi;
        vll_lds[r][c] = (short)f2bf(v - bf2f(hi));
    }
    wvl_lds[tid] = wvl_w[tid];
    __syncthreads();

    f32x4 C1[4];
#pragma unroll
    for (int nt = 0; nt < 4; nt++) {
        float cb = cen_b[(ntb + nt) * 16 + col];
        C1[nt] = (f32x4){cb, cb, cb, cb};
    }
    {
        const int arow = mt * 16 + col;
#pragma unroll
        for (int ks = 0; ks < 4; ks++) {
            const int k0 = ks * 32 + kg * 8;
            short8 Ah = *(const short8*)&vlh_lds[arow][k0];
            short8 Al = *(const short8*)&vll_lds[arow][k0];
#pragma unroll
            for (int nt = 0; nt < 4; nt++) {
                const int brow = ((ntb + nt) * 16 + col) * 128 + k0;
                short8 Bh = *(const short8*)(cenw_hi + brow);
                short8 Bl = *(const short8*)(cenw_lo + brow);
                C1[nt] = __builtin_amdgcn_mfma_f32_16x16x32_bf16(Ah, Bh, C1[nt], 0, 0, 0);
                C1[nt] = __builtin_amdgcn_mfma_f32_16x16x32_bf16(Al, Bh, C1[nt], 0, 0, 0);
                C1[nt] = __builtin_amdgcn_mfma_f32_16x16x32_bf16(Ah, Bl, C1[nt], 0, 0, 0);
            }
        }
    }

    {
        const int r = tid >> 3;
        const int hh = tid & 7;
        const int og = hh * 16;
        float sseg[16];
#pragma unroll
        for (int q = 0; q < 4; q++) {
            float4 v = *(const float4*)&S_lds[r][og + q * 4];
            sseg[q * 4 + 0] = v.x; sseg[q * 4 + 1] = v.y;
            sseg[q * 4 + 2] = v.z; sseg[q * 4 + 3] = v.w;
        }
        const float flag = (off[n0 + r + 1] > off[n0 + r]) ? 1.f : 0.f;
#pragma unroll
        for (int oo = 0; oo < 16; oo++) {
            float acc = wvl_b[oo] * flag;
            const float* wr = &wvl_lds[oo * 16];
#pragma unroll
            for (int jj = 0; jj < 16; jj++) acc = fmaf(wr[jj], sseg[jj], acc);
            agg_lds[r][og + oo] = acc;
        }
    }
    __syncthreads();

#pragma unroll
    for (int nt = 0; nt < 4; nt++) {
        const int c = (ntb + nt) * 16 + col;
#pragma unroll
        for (int r_ = 0; r_ < 4; r_++) {
            const int rr = mt * 16 + kg * 4 + r_;
            float v = ssp(C1[nt][r_] + agg_lds[rr][c]);
            unsigned short hi = f2bf(v);
            vlh_lds[rr][c] = (short)hi;
            vll_lds[rr][c] = (short)f2bf(v - bf2f(hi));
        }
    }
    __syncthreads();

    f32x4 C2[4];
#pragma unroll
    for (int nt = 0; nt < 4; nt++) {
        float ob = out_b[(ntb + nt) * 16 + col];
        C2[nt] = (f32x4){ob, ob, ob, ob};
    }
    {
        const int arow = mt * 16 + col;
#pragma unroll
        for (int ks = 0; ks < 4; ks++) {
            const int k0 = ks * 32 + kg * 8;
            short8 Ah = *(const short8*)&vlh_lds[arow][k0];
            short8 Al = *(const short8*)&vll_lds[arow][k0];
#pragma unroll
            for (int nt = 0; nt < 4; nt++) {
                const int brow = ((ntb + nt) * 16 + col) * 128 + k0;
                short8 Bh = *(const short8*)(outw_hi + brow);
                short8 Bl = *(const short8*)(outw_lo + brow);
                C2[nt] = __builtin_amdgcn_mfma_f32_16x16x32_bf16(Ah, Bh, C2[nt], 0, 0, 0);
                C2[nt] = __builtin_amdgcn_mfma_f32_16x16x32_bf16(Al, Bh, C2[nt], 0, 0, 0);
                C2[nt] = __builtin_amdgcn_mfma_f32_16x16x32_bf16(Ah, Bl, C2[nt], 0, 0, 0);
            }
        }
    }
#pragma unroll
    for (int nt = 0; nt < 4; nt++) {
        const int c = (ntb + nt) * 16 + col;
#pragma unroll
        for (int r_ = 0; r_ < 4; r_++) {
            S_lds[mt * 16 + kg * 4 + r_][c] = C2[nt][r_];
        }
    }
    __syncthreads();

    {
        const int r = tid >> 3;
        const int g = tid & 7;
        float vals[16];
#pragma unroll
        for (int q = 0; q < 4; q++) {
            float4 v = *(const float4*)&S_lds[r][g * 16 + q * 4];
            vals[q * 4 + 0] = v.x; vals[q * 4 + 1] = v.y;
            vals[q * 4 + 2] = v.z; vals[q * 4 + 3] = v.w;
        }
        float s1 = 0.f, s2 = 0.f;
#pragma unroll
        for (int q = 0; q < 16; q++) { s1 += vals[q]; s2 = fmaf(vals[q], vals[q], s2); }
#pragma unroll
        for (int s = 1; s <= 4; s <<= 1) {
            s1 += __shfl_xor(s1, s);
            s2 += __shfl_xor(s2, s);
        }
        const float mean = s1 * (1.f / 128.f);
        const float var  = s2 * (1.f / 128.f) - mean * mean;
        const float inv  = rsqrtf(var + 1e-5f);
        float o[16];
#pragma unroll
        for (int q = 0; q < 16; q++) {
            const int c = g * 16 + q;
            o[q] = (vals[q] - mean) * inv * ln_g[c] + ln_b[c];
        }
        float* op = out + (size_t)(n0 + r) * 128 + g * 16;
#pragma unroll
        for (int q = 0; q < 4; q++) *(float4*)(op + q * 4) = *(float4*)(o + q * 4);
    }
}

extern "C" void kernel_launch(void* const* d_in, const int* in_sizes, int n_in,
                              void* d_out, int out_size, void* d_ws, size_t ws_size,
                              hipStream_t stream)
{
    (void)in_sizes; (void)n_in; (void)out_size; (void)ws_size;
    const float* node_attr = (const float*)d_in[0];
    const int*   edge_index= (const int*)d_in[1];
    const float* edge_attr = (const float*)d_in[2];
    const float* k_w  = (const float*)d_in[3];
    const float* q_w  = (const float*)d_in[4];
    const float* v_w  = (const float*)d_in[5];
    const float* wk1_w= (const float*)d_in[6];  const float* wk1_b= (const float*)d_in[7];
    const float* wk2_w= (const float*)d_in[8];  const float* wk2_b= (const float*)d_in[9];
    const float* wkl_w= (const float*)d_in[10]; const float* wkl_b= (const float*)d_in[11];
    const float* wv1_w= (const float*)d_in[12]; const float* wv1_b= (const float*)d_in[13];
    const float* wv2_w= (const float*)d_in[14]; const float* wv2_b= (const float*)d_in[15];
    const float* wvl_w= (const float*)d_in[16]; const float* wvl_b= (const float*)d_in[17];
    const float* cen_w= (const float*)d_in[18]; const float* cen_b= (const float*)d_in[19];
    const float* out_w= (const float*)d_in[20]; const float* out_b= (const float*)d_in[21];
    const float* ln_g = (const float*)d_in[22]; const float* ln_b = (const float*)d_in[23];
    float* out = (float*)d_out;

    char* ws = (char*)d_ws;
    size_t o = 0;
    auto alloc = [&](size_t bytes) -> void* {
        void* p = ws + o;
        o += (bytes + 255) & ~(size_t)255;
        return p;
    };
    unsigned short* hk_g16 = (unsigned short*)alloc((size_t)NN * 128 * 2);
    float* hv_g   = (float*)alloc((size_t)NN * 128 * 4);
    float* qt_g   = (float*)alloc((size_t)NN * 128 * 4);
    float* qb_g   = (float*)alloc((size_t)NN * 8 * 4);
    unsigned short* S_g16 = (unsigned short*)alloc((size_t)NN * 128 * 2);
    unsigned int* wkv_csr = (unsigned int*)alloc((size_t)EE * 16 * 4);
    // hist aliased into wkv_csr (chunk-major): dead before edge_mlp overwrites
    int* hist     = (int*)wkv_csr;   // NCHUNK*NN*4 = 5.12 MB <= 40.96 MB
    int* tot      = (int*)alloc((size_t)NN * 4);
    int* off      = (int*)alloc((size_t)(NN + 1) * 4);
    int* csr_e    = (int*)alloc((size_t)EE * 4);
    int* csr_col  = (int*)alloc((size_t)EE * 4);
    short* cenw_hi = (short*)alloc(16384 * 2);
    short* cenw_lo = (short*)alloc(16384 * 2);
    short* outw_hi = (short*)alloc(16384 * 2);
    short* outw_lo = (short*)alloc(16384 * 2);
    short* w1k   = (short*)alloc(1024 * 2);
    short* w1v   = (short*)alloc(1024 * 2);
    short* w2k   = (short*)alloc(256 * 2);
    short* w2v   = (short*)alloc(256 * 2);

    hipMemsetAsync(hist, 0, (size_t)NCHUNK * NN * 4, stream);

    prep_w<<<129, 256, 0, stream>>>(cen_w, out_w, wk1_w, wv1_w, wk2_w, wv2_w,
                                    cenw_hi, cenw_lo, outw_hi, outw_lo,
                                    w1k, w1v, w2k, w2v);
    node_pre<<<NN, 128, 0, stream>>>(node_attr, k_w, q_w, v_w, wkl_w, wkl_b,
                                     hk_g16, hv_g, qt_g, qb_g);
    hist_kernel<<<(EE + 255) / 256, 256, 0, stream>>>(edge_index, hist);
    node_tot<<<(NN + 255) / 256, 256, 0, stream>>>(hist, tot);
    scan_tot<<<1, 1024, 0, stream>>>(tot, off);
    chunk_base<<<(NN + 255) / 256, 256, 0, stream>>>(hist, off);
    scatter_det<<<NCHUNK, 64, 0, stream>>>(edge_index, hist, csr_e, csr_col);
    edge_mlp<<<EE / 64, 256, 0, stream>>>(edge_attr,
                                          w1k, wk1_b, w2k, wk2_b,
                                          w1v, wv1_b, w2v, wv2_b,
                                          csr_e, wkv_csr);
    node_attn<<<NN / 4, 256, 0, stream>>>(off, csr_col, wkv_csr, hk_g16, hv_g,
                                          qt_g, qb_g, S_g16);
    node_out<<<NN / 32, 256, 0, stream>>>(off, S_g16, node_attr,
                                          cenw_hi, cenw_lo, cen_b,
                                          outw_hi, outw_lo, out_b,
                                          wvl_w, wvl_b, ln_g, ln_b, out);
}